// Round 15
// baseline (344.732 us; speedup 1.0000x reference)
//
#include <hip/hip_runtime.h>
#include <math.h>

#define B_ 4
#define L_ 64
#define D_ 512
#define DI_ 1024
#define N_ 16
#define DC_ 4
#define R_ 32
#define NL_ 4
#define SD_ 17
#define AD_ 6
#define T_ 256    // 4*L
#define CH3_ 32   // scan chunks
#define TC3_ 8    // T_/CH3_

// bf16 weight segment sizes (elements)
#define NW_IN  (NL_ * 2 * DI_ * D_)   // 4194304
#define NW_OUT (NL_ * D_ * DI_)       // 2097152
#define NW_XP  (NL_ * 64 * DI_)       // 262144
#define NW_TOT (NW_IN + NW_OUT + NW_XP)  // 6553600
#define WCVT_BLOCKS (NW_TOT / 4 / 256)   // 6400

typedef short bf16x8 __attribute__((ext_vector_type(8)));
typedef float f32x4 __attribute__((ext_vector_type(4)));

__device__ __forceinline__ float silu_f(float v) { return v / (1.f + __expf(-v)); }
__device__ __forceinline__ float softplus_f(float v) {
    return fmaxf(v, 0.f) + log1pf(__expf(-fabsf(v)));
}
__device__ __forceinline__ unsigned short f2bs(float f) {
    unsigned u = __float_as_uint(f);
    u += 0x7fffu + ((u >> 16) & 1u);
    return (unsigned short)(u >> 16);
}
__device__ __forceinline__ float bs2f(unsigned short s) {
    return __uint_as_float(((unsigned)s) << 16);
}

// ---------------------------------------------------------------------------
// Merged one-time init: weight cvt + embedding.
// ---------------------------------------------------------------------------
__global__ __launch_bounds__(256) void init_kernel(
    const float* __restrict__ in_w, const float* __restrict__ out_w,
    const float* __restrict__ xp_w, unsigned short* __restrict__ wb,
    const float* __restrict__ states, const float* __restrict__ actions,
    const float* __restrict__ rtg, const float* __restrict__ ctg,
    const int* __restrict__ ts,
    const float* __restrict__ es_w, const float* __restrict__ es_b,
    const float* __restrict__ ea_w, const float* __restrict__ ea_b,
    const float* __restrict__ er_w, const float* __restrict__ er_b,
    const float* __restrict__ ec_w, const float* __restrict__ ec_b,
    const float* __restrict__ et_w, float* __restrict__ x)
{
    if (blockIdx.x < WCVT_BLOCKS) {
        const int i = blockIdx.x * 256 + threadIdx.x;   // float4 index
        const int e = i * 4;
        const float* src; int off;
        if (e < NW_IN)               { src = in_w;  off = e; }
        else if (e < NW_IN + NW_OUT) { src = out_w; off = e - NW_IN; }
        else                         { src = xp_w;  off = e - NW_IN - NW_OUT; }
        const float4 v = *(const float4*)(src + off);
        ushort4 o;
        o.x = f2bs(v.x); o.y = f2bs(v.y); o.z = f2bs(v.z); o.w = f2bs(v.w);
        *(ushort4*)(wb + e) = o;
    } else {
        const int bl = blockIdx.x - WCVT_BLOCKS;   // 0..255 = b*64+l
#pragma unroll
        for (int j = 0; j < 2; ++j) {
            const int d = threadIdx.x + j * 256;
            const float te = et_w[(size_t)ts[bl] * D_ + d];
            const float r = rtg[bl] * er_w[d] + er_b[d] + te;
            const float c = ctg[bl] * ec_w[d] + ec_b[d] + te;
            float s = es_b[d] + te;
#pragma unroll
            for (int k = 0; k < SD_; ++k) s += states[bl * SD_ + k] * es_w[d * SD_ + k];
            float a = ea_b[d] + te;
#pragma unroll
            for (int k = 0; k < AD_; ++k) a += actions[bl * AD_ + k] * ea_w[d * AD_ + k];
            float* xp = x + (size_t)bl * 4 * D_;
            xp[0 * D_ + d] = r;
            xp[1 * D_ + d] = c;
            xp[2 * D_ + d] = s;
            xp[3 * D_ + d] = a;
        }
    }
}

// ---------------------------------------------------------------------------
// LayerNorm (+ optional residual partial sum from split-K out_proj).
// MODE 0: ln(x) -> bf16.  MODE 1: x += p0+p1 (stored), ln -> bf16.
// MODE 2: x += p0+p1, ln -> fp32.
// ---------------------------------------------------------------------------
template <int MODE>
__global__ __launch_bounds__(256) void ln2_kernel(
    float* __restrict__ x, const float* __restrict__ p0,
    const float* __restrict__ p1,
    const float* __restrict__ w, const float* __restrict__ b,
    void* __restrict__ o_)
{
    const int tok = blockIdx.x;
    const int tid = threadIdx.x;
    float2 v = reinterpret_cast<float2*>(x + (size_t)tok * D_)[tid];
    if (MODE >= 1) {
        const float2 a0 = reinterpret_cast<const float2*>(p0 + (size_t)tok * D_)[tid];
        const float2 a1 = reinterpret_cast<const float2*>(p1 + (size_t)tok * D_)[tid];
        v.x += a0.x + a1.x;
        v.y += a0.y + a1.y;
        reinterpret_cast<float2*>(x + (size_t)tok * D_)[tid] = v;
    }
    float s = v.x + v.y;
#pragma unroll
    for (int off = 1; off < 64; off <<= 1) s += __shfl_xor(s, off);
    __shared__ float red[8];
    const int wv = tid >> 6;
    if ((tid & 63) == 0) red[wv] = s;
    __syncthreads();
    const float mean = (red[0] + red[1] + red[2] + red[3]) * (1.f / D_);
    const float dx = v.x - mean, dy = v.y - mean;
    float q = dx * dx + dy * dy;
#pragma unroll
    for (int off = 1; off < 64; off <<= 1) q += __shfl_xor(q, off);
    if ((tid & 63) == 0) red[4 + wv] = q;
    __syncthreads();
    const float var = (red[4] + red[5] + red[6] + red[7]) * (1.f / D_);
    const float r = rsqrtf(var + 1e-5f);
    const int d0 = tid * 2;
    const float o0 = dx * r * w[d0] + b[d0];
    const float o1 = dy * r * w[d0 + 1] + b[d0 + 1];
    if (MODE == 2) {
        float* o = (float*)o_;
        o[(size_t)tok * D_ + d0] = o0;
        o[(size_t)tok * D_ + d0 + 1] = o1;
    } else {
        unsigned short* o = (unsigned short*)o_;
        o[(size_t)tok * D_ + d0] = f2bs(o0);
        o[(size_t)tok * D_ + d0 + 1] = f2bs(o1);
    }
}

// ---------------------------------------------------------------------------
// in_proj GEMM with FUSED conv+silu epilogue (R13, kept).
// ---------------------------------------------------------------------------
__global__ __launch_bounds__(256) void inproj_kernel(
    const unsigned short* __restrict__ A, const unsigned short* __restrict__ W,
    const float* __restrict__ cw, const float* __restrict__ cb,
    unsigned short* __restrict__ xcb, unsigned short* __restrict__ zs)
{
    __shared__ unsigned short sxm[80][72];   // padded
    const int lane = threadIdx.x & 63, wid = threadIdx.x >> 6;
    const int r = lane & 15, kq = lane >> 4;
    const int m0 = blockIdx.y * 64;
    const int n0 = blockIdx.x * 64;
    const bool is_xm = (n0 < DI_);
    const int wm = m0 + (wid >> 1) * 32;
    const int wn = n0 + (wid & 1) * 32;
    f32x4 acc[2][2] = {};
    f32x4 accx[2] = {};
    int xrow = m0 - 16 + r;
    if (xrow < 0) xrow = 0;     // clamped reads are masked at consume time
#pragma unroll 4
    for (int k0 = 0; k0 < D_; k0 += 32) {
        bf16x8 a[2], b[2];
#pragma unroll
        for (int i = 0; i < 2; ++i)
            a[i] = *(const bf16x8*)(A + (size_t)(wm + i * 16 + r) * D_ + k0 + kq * 8);
#pragma unroll
        for (int j = 0; j < 2; ++j)
            b[j] = *(const bf16x8*)(W + (size_t)(wn + j * 16 + r) * D_ + k0 + kq * 8);
#pragma unroll
        for (int i = 0; i < 2; ++i)
#pragma unroll
            for (int j = 0; j < 2; ++j)
                acc[i][j] = __builtin_amdgcn_mfma_f32_16x16x32_bf16(a[i], b[j], acc[i][j], 0, 0, 0);
        if (is_xm) {
            const bf16x8 ax = *(const bf16x8*)(A + (size_t)xrow * D_ + k0 + kq * 8);
#pragma unroll
            for (int j = 0; j < 2; ++j)
                accx[j] = __builtin_amdgcn_mfma_f32_16x16x32_bf16(ax, b[j], accx[j], 0, 0, 0);
        }
    }
    // C/D layout: col = lane&15, row = (lane>>4)*4 + reg
    if (!is_xm) {
#pragma unroll
        for (int i = 0; i < 2; ++i)
#pragma unroll
            for (int j = 0; j < 2; ++j)
#pragma unroll
                for (int g = 0; g < 4; ++g) {
                    const int row = wm + i * 16 + kq * 4 + g;
                    const int col = wn + j * 16 + r - DI_;
                    zs[(size_t)row * DI_ + col] = f2bs(silu_f(acc[i][j][g]));
                }
        return;   // block-uniform branch
    }
#pragma unroll
    for (int i = 0; i < 2; ++i)
#pragma unroll
        for (int j = 0; j < 2; ++j)
#pragma unroll
            for (int g = 0; g < 4; ++g) {
                const int srow = 16 + (wm - m0) + i * 16 + kq * 4 + g;
                const int scol = (wn - n0) + j * 16 + r;
                sxm[srow][scol] = f2bs(acc[i][j][g]);
            }
#pragma unroll
    for (int j = 0; j < 2; ++j)
#pragma unroll
        for (int g = 0; g < 4; ++g) {
            const int srow = kq * 4 + g;               // rows m0-16..m0-1
            const int scol = (wn - n0) + j * 16 + r;
            sxm[srow][scol] = f2bs(accx[j][g]);
        }
    __syncthreads();
    for (int e = threadIdx.x; e < 64 * 64; e += 256) {
        const int col = e & 63, rrel = e >> 6;
        const int grow = m0 + rrel;
        const int t = grow & (T_ - 1);
        const int d = n0 + col;
        const float4 w4 = ((const float4*)cw)[d];
        float a = cb[d];
#pragma unroll
        for (int k = 0; k < DC_; ++k) {
            if (t - 3 + k >= 0) {
                const float wk = (k == 0) ? w4.x : (k == 1) ? w4.y
                               : (k == 2) ? w4.z : w4.w;
                a += wk * bs2f(sxm[16 + rrel - 3 + k][col]);
            }
        }
        xcb[(size_t)grow * DI_ + d] = f2bs(silu_f(a));
    }
}

// ---------------------------------------------------------------------------
// xp GEMM (unchanged).
// ---------------------------------------------------------------------------
__global__ __launch_bounds__(256) void xp_kernel(
    const unsigned short* __restrict__ xcb, const unsigned short* __restrict__ Wb,
    float* __restrict__ dbc)
{
    __shared__ float red[4][16][64];
    const int tid = threadIdx.x;
    const int wid = tid >> 6, lane = tid & 63;
    const int r = lane & 15, kq = lane >> 4;
    const int m0 = blockIdx.x * 16;
    f32x4 acc4[4] = {};
    const int k00 = wid * 256;
#pragma unroll
    for (int ks = 0; ks < 8; ++ks) {
        const int k0 = k00 + ks * 32;
        const bf16x8 a = *(const bf16x8*)(xcb + (size_t)(m0 + r) * DI_ + k0 + kq * 8);
#pragma unroll
        for (int j = 0; j < 4; ++j) {
            const bf16x8 bfr = *(const bf16x8*)(Wb + (size_t)(j * 16 + r) * DI_ + k0 + kq * 8);
            acc4[j] = __builtin_amdgcn_mfma_f32_16x16x32_bf16(a, bfr, acc4[j], 0, 0, 0);
        }
    }
#pragma unroll
    for (int j = 0; j < 4; ++j)
#pragma unroll
        for (int g = 0; g < 4; ++g)
            red[wid][kq * 4 + g][j * 16 + r] = acc4[j][g];
    __syncthreads();
    for (int i = tid; i < 1024; i += 256) {
        const int row = i >> 6, col = i & 63;
        const float s = red[0][row][col] + red[1][row][col] +
                        red[2][row][col] + red[3][row][col];
        dbc[(size_t)(m0 + row) * 64 + col] = s;
    }
}

// ---------------------------------------------------------------------------
// Selective scan v5: 3-kernel COALESCED restructure.
// Invariant bottleneck of v2-v4 (~30us/layer): block d-range of 8 made every
// u/z/y access 16B-per-2KB-row strided. Fix: thread <-> d (256 d per block),
// chunk moved to the GRID; cross-block chunk combine in a tiny p2.
// All u/z/y/delta accesses: 128B contiguous per wave. dbc/B/C rows:
// block-uniform broadcast (L1). S/P/h_in: 64B per thread, coalesced.
// Arithmetic identical to v3 (same softplus/exp/dsum formulas).
// ---------------------------------------------------------------------------
// p1: local chunk scan. grid 512 = b(4) x c(32) x dband(4); thread=d.
__global__ __launch_bounds__(256) void scan_p1_kernel(
    const unsigned short* __restrict__ xcb, const float* __restrict__ dbc,
    const float* __restrict__ dtw, const float* __restrict__ dtbias,
    const float* __restrict__ A_log,
    float* __restrict__ Sg, float* __restrict__ Pg, float* __restrict__ dltg)
{
    const int tid = threadIdx.x;
    const int b = blockIdx.x >> 7;
    const int c = (blockIdx.x >> 2) & 31;
    const int dband = blockIdx.x & 3;
    const int d = dband * 256 + tid;
    const int row0 = b * T_ + c * TC3_;
    float4 w4[8];
    {
        const float4* Wp = (const float4*)(dtw + (size_t)d * R_);
#pragma unroll
        for (int q = 0; q < 8; ++q) w4[q] = Wp[q];
    }
    const float bias = dtbias[d];
    float Av[N_];
    {
        const float4* Alp = (const float4*)(A_log + (size_t)d * N_);
#pragma unroll
        for (int q = 0; q < 4; ++q) {
            const float4 v = Alp[q];
            Av[q * 4 + 0] = -__expf(v.x);
            Av[q * 4 + 1] = -__expf(v.y);
            Av[q * 4 + 2] = -__expf(v.z);
            Av[q * 4 + 3] = -__expf(v.w);
        }
    }
    float h[N_];
#pragma unroll
    for (int n = 0; n < N_; ++n) h[n] = 0.f;
    float dsum = 0.f;
#pragma unroll
    for (int t = 0; t < TC3_; ++t) {
        const int row = row0 + t;
        const float4* Ap = (const float4*)(dbc + (size_t)row * 64);
        float acc = bias;
#pragma unroll
        for (int q = 0; q < 8; ++q) {
            const float4 a4 = Ap[q];
            acc += a4.x * w4[q].x + a4.y * w4[q].y + a4.z * w4[q].z + a4.w * w4[q].w;
        }
        const float dt_t = softplus_f(acc);
        dltg[(size_t)row * DI_ + d] = dt_t;
        dsum += dt_t;
        const float dbu = dt_t * bs2f(xcb[(size_t)row * DI_ + d]);
#pragma unroll
        for (int q = 0; q < 4; ++q) {
            const float4 b4 = Ap[8 + q];   // dbc cols 32..47 = B
            h[q * 4 + 0] = __expf(dt_t * Av[q * 4 + 0]) * h[q * 4 + 0] + dbu * b4.x;
            h[q * 4 + 1] = __expf(dt_t * Av[q * 4 + 1]) * h[q * 4 + 1] + dbu * b4.y;
            h[q * 4 + 2] = __expf(dt_t * Av[q * 4 + 2]) * h[q * 4 + 2] + dbu * b4.z;
            h[q * 4 + 3] = __expf(dt_t * Av[q * 4 + 3]) * h[q * 4 + 3] + dbu * b4.w;
        }
    }
    const size_t base = (((size_t)b * CH3_ + c) * DI_ + d) * N_;
#pragma unroll
    for (int n = 0; n < N_; ++n) {
        Sg[base + n] = h[n];
        Pg[base + n] = __expf(Av[n] * dsum);
    }
}

// p2: sequential chunk combine per (b,d,n). grid 256 x 256 thr.
__global__ __launch_bounds__(256) void scan_p2_kernel(
    const float* __restrict__ Pg, float* __restrict__ Sg)
{
    const int i = blockIdx.x * 256 + threadIdx.x;   // 65536 = B * DI * N
    const int b = i >> 14;
    const int dn = i & 16383;
    float hcur = 0.f;
#pragma unroll
    for (int c = 0; c < CH3_; ++c) {
        const size_t idx = ((size_t)b * CH3_ + c) * (DI_ * N_) + dn;
        const float t2 = Pg[idx] * hcur + Sg[idx];
        Sg[idx] = hcur;         // becomes h_in for chunk c
        hcur = t2;
    }
}

// p3: re-scan from h_in, emit gated y. Same geometry as p1.
__global__ __launch_bounds__(256) void scan_p3_kernel(
    const unsigned short* __restrict__ xcb, const float* __restrict__ dbc,
    const float* __restrict__ dltg, const float* __restrict__ A_log,
    const float* __restrict__ Dp, const float* __restrict__ Sg,
    const unsigned short* __restrict__ zs, unsigned short* __restrict__ ygb)
{
    const int tid = threadIdx.x;
    const int b = blockIdx.x >> 7;
    const int c = (blockIdx.x >> 2) & 31;
    const int dband = blockIdx.x & 3;
    const int d = dband * 256 + tid;
    const int row0 = b * T_ + c * TC3_;
    float Av[N_];
    {
        const float4* Alp = (const float4*)(A_log + (size_t)d * N_);
#pragma unroll
        for (int q = 0; q < 4; ++q) {
            const float4 v = Alp[q];
            Av[q * 4 + 0] = -__expf(v.x);
            Av[q * 4 + 1] = -__expf(v.y);
            Av[q * 4 + 2] = -__expf(v.z);
            Av[q * 4 + 3] = -__expf(v.w);
        }
    }
    float h[N_];
    {
        const size_t base = (((size_t)b * CH3_ + c) * DI_ + d) * N_;
#pragma unroll
        for (int q = 0; q < 4; ++q) {
            const float4 v = *(const float4*)(Sg + base + q * 4);
            h[q * 4 + 0] = v.x; h[q * 4 + 1] = v.y;
            h[q * 4 + 2] = v.z; h[q * 4 + 3] = v.w;
        }
    }
    const float Dd = Dp[d];
#pragma unroll
    for (int t = 0; t < TC3_; ++t) {
        const int row = row0 + t;
        const float dt_t = dltg[(size_t)row * DI_ + d];
        const float ut = bs2f(xcb[(size_t)row * DI_ + d]);
        const float dbu = dt_t * ut;
        const float4* Ap = (const float4*)(dbc + (size_t)row * 64);
        float y = ut * Dd;
#pragma unroll
        for (int q = 0; q < 4; ++q) {
            const float4 b4 = Ap[8 + q];    // B
            const float4 c4 = Ap[12 + q];   // C
            h[q * 4 + 0] = __expf(dt_t * Av[q * 4 + 0]) * h[q * 4 + 0] + dbu * b4.x;
            h[q * 4 + 1] = __expf(dt_t * Av[q * 4 + 1]) * h[q * 4 + 1] + dbu * b4.y;
            h[q * 4 + 2] = __expf(dt_t * Av[q * 4 + 2]) * h[q * 4 + 2] + dbu * b4.z;
            h[q * 4 + 3] = __expf(dt_t * Av[q * 4 + 3]) * h[q * 4 + 3] + dbu * b4.w;
            y += h[q * 4 + 0] * c4.x + h[q * 4 + 1] * c4.y
               + h[q * 4 + 2] * c4.z + h[q * 4 + 3] * c4.w;
        }
        ygb[(size_t)row * DI_ + d] = f2bs(y * bs2f(zs[(size_t)row * DI_ + d]));
    }
}

// ---------------------------------------------------------------------------
// out_proj split-K=2 (R13).
// ---------------------------------------------------------------------------
__global__ __launch_bounds__(256) void outproj_kernel(
    const unsigned short* __restrict__ A, const unsigned short* __restrict__ W,
    float* __restrict__ p)
{
    const int lane = threadIdx.x & 63, wid = threadIdx.x >> 6;
    const int r = lane & 15, kq = lane >> 4;
    const int wm = blockIdx.y * 64 + (wid >> 1) * 32;
    const int wn = blockIdx.x * 64 + (wid & 1) * 32;
    const int kb = blockIdx.z * 512;
    f32x4 acc[2][2] = {};
#pragma unroll 4
    for (int k0 = 0; k0 < 512; k0 += 32) {
        bf16x8 a[2], b[2];
#pragma unroll
        for (int i = 0; i < 2; ++i)
            a[i] = *(const bf16x8*)(A + (size_t)(wm + i * 16 + r) * DI_ + kb + k0 + kq * 8);
#pragma unroll
        for (int j = 0; j < 2; ++j)
            b[j] = *(const bf16x8*)(W + (size_t)(wn + j * 16 + r) * DI_ + kb + k0 + kq * 8);
#pragma unroll
        for (int i = 0; i < 2; ++i)
#pragma unroll
            for (int j = 0; j < 2; ++j)
                acc[i][j] = __builtin_amdgcn_mfma_f32_16x16x32_bf16(a[i], b[j], acc[i][j], 0, 0, 0);
    }
#pragma unroll
    for (int i = 0; i < 2; ++i)
#pragma unroll
        for (int j = 0; j < 2; ++j)
#pragma unroll
            for (int g = 0; g < 4; ++g) {
                const int row = wm + i * 16 + kq * 4 + g;
                const int col = wn + j * 16 + r;
                p[(size_t)blockIdx.z * (1024 * 512) + (size_t)row * 512 + col] = acc[i][j][g];
            }
}

// ---------------------------------------------------------------------------
// Heads
// ---------------------------------------------------------------------------
__global__ __launch_bounds__(256) void heads_kernel(
    const float* __restrict__ xn,
    const float* __restrict__ ps_w, const float* __restrict__ ps_b,
    const float* __restrict__ pa_w, const float* __restrict__ pa_b,
    float* __restrict__ out)
{
    const int idx = blockIdx.x * 4 + (threadIdx.x >> 6);
    const int lane = threadIdx.x & 63;
    const int bl = idx / 23, j = idx % 23;
    const float* tok;
    const float* wrow;
    float bias;
    float* dst;
    if (j < SD_) {
        tok = xn + ((size_t)bl * 4 + 3) * D_;
        wrow = ps_w + (size_t)j * D_;
        bias = ps_b[j];
        dst = out + (size_t)bl * SD_ + j;
    } else {
        const int jj = j - SD_;
        tok = xn + ((size_t)bl * 4 + 2) * D_;
        wrow = pa_w + (size_t)jj * D_;
        bias = pa_b[jj];
        dst = out + (size_t)B_ * L_ * SD_ + (size_t)bl * AD_ + jj;
    }
    float s = 0.f;
    for (int dd = lane; dd < D_; dd += 64) s += tok[dd] * wrow[dd];
#pragma unroll
    for (int off = 1; off < 64; off <<= 1) s += __shfl_xor(s, off);
    if (lane == 0) *dst = s + bias;
}

// ---------------------------------------------------------------------------
extern "C" void kernel_launch(void* const* d_in, const int* in_sizes, int n_in,
                              void* d_out, int out_size, void* d_ws, size_t ws_size,
                              hipStream_t stream)
{
    const float* states  = (const float*)d_in[0];
    const float* actions = (const float*)d_in[1];
    const float* rtg     = (const float*)d_in[2];
    const float* ctg     = (const float*)d_in[3];
    const int*   ts      = (const int*)d_in[4];
    const float* es_w = (const float*)d_in[5];  const float* es_b = (const float*)d_in[6];
    const float* ea_w = (const float*)d_in[7];  const float* ea_b = (const float*)d_in[8];
    const float* er_w = (const float*)d_in[9];  const float* er_b = (const float*)d_in[10];
    const float* ec_w = (const float*)d_in[11]; const float* ec_b = (const float*)d_in[12];
    const float* et_w = (const float*)d_in[13];
    const float* ln_w = (const float*)d_in[14]; const float* ln_b = (const float*)d_in[15];
    const float* in_w = (const float*)d_in[16];
    const float* conv_w = (const float*)d_in[17]; const float* conv_b = (const float*)d_in[18];
    const float* xp_w = (const float*)d_in[19];
    const float* dtp_w = (const float*)d_in[20]; const float* dtp_b = (const float*)d_in[21];
    const float* A_log = (const float*)d_in[22]; const float* Dp = (const float*)d_in[23];
    const float* out_w = (const float*)d_in[24];
    const float* fn_w = (const float*)d_in[25]; const float* fn_b = (const float*)d_in[26];
    const float* ps_w = (const float*)d_in[27]; const float* ps_b = (const float*)d_in[28];
    const float* pa_w = (const float*)d_in[29]; const float* pa_b = (const float*)d_in[30];
    float* out = (float*)d_out;

    // workspace layout (floats then bf16); ~50 MB total
    float* ws   = (float*)d_ws;
    float* x    = ws;                    // 524288 f32
    float* xn   = x + 524288;            // 524288 f32 (final LN out)
    float* p    = xn + 524288;           // 1048576 f32 (out_proj partials p0|p1)
    float* dbc  = p + 1048576;           // 65536 f32
    float* Sg   = dbc + 65536;           // 2097152 f32 (scan chunk states)
    float* Pg   = Sg + 2097152;          // 2097152 f32 (scan chunk decay)
    float* dltg = Pg + 2097152;          // 1048576 f32 (delta)
    unsigned short* xnb = (unsigned short*)(dltg + 1048576);  // 524288 bf16
    unsigned short* xcb = xnb + 524288;                    // 1048576 bf16
    unsigned short* zs  = xcb + 1048576;                   // 1048576 bf16
    unsigned short* ygb = zs + 1048576;                    // 1048576 bf16
    unsigned short* wb  = ygb + 1048576;                   // 6553600 bf16
    unsigned short* wb_in  = wb;
    unsigned short* wb_out = wb + NW_IN;
    unsigned short* wb_xp  = wb + NW_IN + NW_OUT;

    init_kernel<<<WCVT_BLOCKS + B_ * L_, 256, 0, stream>>>(
        in_w, out_w, xp_w, wb,
        states, actions, rtg, ctg, ts,
        es_w, es_b, ea_w, ea_b, er_w, er_b, ec_w, ec_b, et_w, x);

    for (int i = 0; i < NL_; ++i) {
        if (i == 0)
            ln2_kernel<0><<<B_ * T_, 256, 0, stream>>>(
                x, nullptr, nullptr, ln_w, ln_b, xnb);
        else
            ln2_kernel<1><<<B_ * T_, 256, 0, stream>>>(
                x, p, p + 524288, ln_w + i * D_, ln_b + i * D_, xnb);
        // in_proj + conv + silu fused -> xcb | zs
        inproj_kernel<<<dim3(32, 16), 256, 0, stream>>>(
            xnb, wb_in + (size_t)i * 2 * DI_ * D_,
            conv_w + i * DI_ * DC_, conv_b + i * DI_, xcb, zs);
        // xp GEMM -> dbc
        xp_kernel<<<64, 256, 0, stream>>>(
            xcb, wb_xp + (size_t)i * 64 * DI_, dbc);
        // scan: coalesced 3-kernel pipeline
        scan_p1_kernel<<<512, 256, 0, stream>>>(
            xcb, dbc, dtp_w + (size_t)i * DI_ * R_, dtp_b + i * DI_,
            A_log + (size_t)i * DI_ * N_, Sg, Pg, dltg);
        scan_p2_kernel<<<256, 256, 0, stream>>>(Pg, Sg);
        scan_p3_kernel<<<512, 256, 0, stream>>>(
            xcb, dbc, dltg, A_log + (size_t)i * DI_ * N_,
            Dp + i * DI_, Sg, zs, ygb);
        // out_proj split-K=2 -> p0|p1 (summed in next ln)
        outproj_kernel<<<dim3(8, 16, 2), 256, 0, stream>>>(
            ygb, wb_out + (size_t)i * D_ * DI_, p);
    }

    ln2_kernel<2><<<B_ * T_, 256, 0, stream>>>(x, p, p + 524288, fn_w, fn_b, xn);
    heads_kernel<<<(B_ * L_ * 23) / 4, 256, 0, stream>>>(xn, ps_w, ps_b, pa_w, pa_b, out);
}

// Round 16
// 287.093 us; speedup vs baseline: 1.2008x; 1.2008x over previous
//
#include <hip/hip_runtime.h>
#include <math.h>

#define B_ 4
#define L_ 64
#define D_ 512
#define DI_ 1024
#define N_ 16
#define DC_ 4
#define R_ 32
#define NL_ 4
#define SD_ 17
#define AD_ 6
#define T_ 256    // 4*L
#define CH3_ 32   // scan chunks
#define TC3_ 8    // T_/CH3_
#define DL3_ 8    // d-lanes per group
#define XTS_ 1032 // transposed row stride (B*T + 8 pad)

// bf16 weight segment sizes (elements)
#define NW_IN  (NL_ * 2 * DI_ * D_)   // 4194304
#define NW_OUT (NL_ * D_ * DI_)       // 2097152
#define NW_XP  (NL_ * 64 * DI_)       // 262144
#define NW_TOT (NW_IN + NW_OUT + NW_XP)  // 6553600
#define WCVT_BLOCKS (NW_TOT / 4 / 256)   // 6400

typedef short bf16x8 __attribute__((ext_vector_type(8)));
typedef float f32x4 __attribute__((ext_vector_type(4)));

__device__ __forceinline__ float silu_f(float v) { return v / (1.f + __expf(-v)); }
__device__ __forceinline__ float softplus_f(float v) {
    return fmaxf(v, 0.f) + log1pf(__expf(-fabsf(v)));
}
__device__ __forceinline__ unsigned short f2bs(float f) {
    unsigned u = __float_as_uint(f);
    u += 0x7fffu + ((u >> 16) & 1u);
    return (unsigned short)(u >> 16);
}
__device__ __forceinline__ float bs2f(unsigned short s) {
    return __uint_as_float(((unsigned)s) << 16);
}

// ---------------------------------------------------------------------------
// Merged one-time init: weight cvt + embedding.
// ---------------------------------------------------------------------------
__global__ __launch_bounds__(256) void init_kernel(
    const float* __restrict__ in_w, const float* __restrict__ out_w,
    const float* __restrict__ xp_w, unsigned short* __restrict__ wb,
    const float* __restrict__ states, const float* __restrict__ actions,
    const float* __restrict__ rtg, const float* __restrict__ ctg,
    const int* __restrict__ ts,
    const float* __restrict__ es_w, const float* __restrict__ es_b,
    const float* __restrict__ ea_w, const float* __restrict__ ea_b,
    const float* __restrict__ er_w, const float* __restrict__ er_b,
    const float* __restrict__ ec_w, const float* __restrict__ ec_b,
    const float* __restrict__ et_w, float* __restrict__ x)
{
    if (blockIdx.x < WCVT_BLOCKS) {
        const int i = blockIdx.x * 256 + threadIdx.x;   // float4 index
        const int e = i * 4;
        const float* src; int off;
        if (e < NW_IN)               { src = in_w;  off = e; }
        else if (e < NW_IN + NW_OUT) { src = out_w; off = e - NW_IN; }
        else                         { src = xp_w;  off = e - NW_IN - NW_OUT; }
        const float4 v = *(const float4*)(src + off);
        ushort4 o;
        o.x = f2bs(v.x); o.y = f2bs(v.y); o.z = f2bs(v.z); o.w = f2bs(v.w);
        *(ushort4*)(wb + e) = o;
    } else {
        const int bl = blockIdx.x - WCVT_BLOCKS;   // 0..255 = b*64+l
#pragma unroll
        for (int j = 0; j < 2; ++j) {
            const int d = threadIdx.x + j * 256;
            const float te = et_w[(size_t)ts[bl] * D_ + d];
            const float r = rtg[bl] * er_w[d] + er_b[d] + te;
            const float c = ctg[bl] * ec_w[d] + ec_b[d] + te;
            float s = es_b[d] + te;
#pragma unroll
            for (int k = 0; k < SD_; ++k) s += states[bl * SD_ + k] * es_w[d * SD_ + k];
            float a = ea_b[d] + te;
#pragma unroll
            for (int k = 0; k < AD_; ++k) a += actions[bl * AD_ + k] * ea_w[d * AD_ + k];
            float* xp = x + (size_t)bl * 4 * D_;
            xp[0 * D_ + d] = r;
            xp[1 * D_ + d] = c;
            xp[2 * D_ + d] = s;
            xp[3 * D_ + d] = a;
        }
    }
}

// ---------------------------------------------------------------------------
// LayerNorm (+ optional residual partial sum from split-K out_proj).
// MODE 0: ln(x) -> bf16.  MODE 1: x += p0+p1 (stored), ln -> bf16.
// MODE 2: x += p0+p1, ln -> fp32.
// ---------------------------------------------------------------------------
template <int MODE>
__global__ __launch_bounds__(256) void ln2_kernel(
    float* __restrict__ x, const float* __restrict__ p0,
    const float* __restrict__ p1,
    const float* __restrict__ w, const float* __restrict__ b,
    void* __restrict__ o_)
{
    const int tok = blockIdx.x;
    const int tid = threadIdx.x;
    float2 v = reinterpret_cast<float2*>(x + (size_t)tok * D_)[tid];
    if (MODE >= 1) {
        const float2 a0 = reinterpret_cast<const float2*>(p0 + (size_t)tok * D_)[tid];
        const float2 a1 = reinterpret_cast<const float2*>(p1 + (size_t)tok * D_)[tid];
        v.x += a0.x + a1.x;
        v.y += a0.y + a1.y;
        reinterpret_cast<float2*>(x + (size_t)tok * D_)[tid] = v;
    }
    float s = v.x + v.y;
#pragma unroll
    for (int off = 1; off < 64; off <<= 1) s += __shfl_xor(s, off);
    __shared__ float red[8];
    const int wv = tid >> 6;
    if ((tid & 63) == 0) red[wv] = s;
    __syncthreads();
    const float mean = (red[0] + red[1] + red[2] + red[3]) * (1.f / D_);
    const float dx = v.x - mean, dy = v.y - mean;
    float q = dx * dx + dy * dy;
#pragma unroll
    for (int off = 1; off < 64; off <<= 1) q += __shfl_xor(q, off);
    if ((tid & 63) == 0) red[4 + wv] = q;
    __syncthreads();
    const float var = (red[4] + red[5] + red[6] + red[7]) * (1.f / D_);
    const float r = rsqrtf(var + 1e-5f);
    const int d0 = tid * 2;
    const float o0 = dx * r * w[d0] + b[d0];
    const float o1 = dy * r * w[d0 + 1] + b[d0 + 1];
    if (MODE == 2) {
        float* o = (float*)o_;
        o[(size_t)tok * D_ + d0] = o0;
        o[(size_t)tok * D_ + d0 + 1] = o1;
    } else {
        unsigned short* o = (unsigned short*)o_;
        o[(size_t)tok * D_ + d0] = f2bs(o0);
        o[(size_t)tok * D_ + d0 + 1] = f2bs(o1);
    }
}

// ---------------------------------------------------------------------------
// in_proj GEMM with FUSED conv+silu epilogue + transposed side-copies.
// xm blocks: conv+silu -> xcb (normal, for xp) AND xcbT (transposed, for
//            the scan's vector u-loads) via LDS transpose.
// z blocks : silu(z) staged in LDS -> zsT (transposed only; scan is the
//            sole consumer).
// ---------------------------------------------------------------------------
__global__ __launch_bounds__(256) void inproj_kernel(
    const unsigned short* __restrict__ A, const unsigned short* __restrict__ W,
    const float* __restrict__ cw, const float* __restrict__ cb,
    unsigned short* __restrict__ xcb, unsigned short* __restrict__ xcbT,
    unsigned short* __restrict__ zsT)
{
    __shared__ unsigned short sxm[80][72];    // xm staging / z staging
    __shared__ unsigned short conv_s[64][72]; // conv output staging
    const int lane = threadIdx.x & 63, wid = threadIdx.x >> 6;
    const int r = lane & 15, kq = lane >> 4;
    const int m0 = blockIdx.y * 64;
    const int n0 = blockIdx.x * 64;
    const bool is_xm = (n0 < DI_);
    const int wm = m0 + (wid >> 1) * 32;
    const int wn = n0 + (wid & 1) * 32;
    f32x4 acc[2][2] = {};
    f32x4 accx[2] = {};
    int xrow = m0 - 16 + r;
    if (xrow < 0) xrow = 0;     // clamped reads are masked at consume time
#pragma unroll 4
    for (int k0 = 0; k0 < D_; k0 += 32) {
        bf16x8 a[2], b[2];
#pragma unroll
        for (int i = 0; i < 2; ++i)
            a[i] = *(const bf16x8*)(A + (size_t)(wm + i * 16 + r) * D_ + k0 + kq * 8);
#pragma unroll
        for (int j = 0; j < 2; ++j)
            b[j] = *(const bf16x8*)(W + (size_t)(wn + j * 16 + r) * D_ + k0 + kq * 8);
#pragma unroll
        for (int i = 0; i < 2; ++i)
#pragma unroll
            for (int j = 0; j < 2; ++j)
                acc[i][j] = __builtin_amdgcn_mfma_f32_16x16x32_bf16(a[i], b[j], acc[i][j], 0, 0, 0);
        if (is_xm) {
            const bf16x8 ax = *(const bf16x8*)(A + (size_t)xrow * D_ + k0 + kq * 8);
#pragma unroll
            for (int j = 0; j < 2; ++j)
                accx[j] = __builtin_amdgcn_mfma_f32_16x16x32_bf16(ax, b[j], accx[j], 0, 0, 0);
        }
    }
    // C/D layout: col = lane&15, row = (lane>>4)*4 + reg
    if (!is_xm) {
        // stage silu(z) tile in LDS (rows 0..63 of sxm)
#pragma unroll
        for (int i = 0; i < 2; ++i)
#pragma unroll
            for (int j = 0; j < 2; ++j)
#pragma unroll
                for (int g = 0; g < 4; ++g) {
                    const int lrow = (wm - m0) + i * 16 + kq * 4 + g;
                    const int lcol = (wn - n0) + j * 16 + r;
                    sxm[lrow][lcol] = f2bs(silu_f(acc[i][j][g]));
                }
        __syncthreads();
        // transposed write: zsT[(n0-DI)+dcol][m0 + tq*16 .. +15]
        {
            const int dcol = threadIdx.x >> 2, tq = threadIdx.x & 3;
            bf16x8 v0, v1;
#pragma unroll
            for (int j = 0; j < 8; ++j) {
                v0[j] = (short)sxm[tq * 16 + j][dcol];
                v1[j] = (short)sxm[tq * 16 + 8 + j][dcol];
            }
            unsigned short* dst = zsT + (size_t)(n0 - DI_ + dcol) * XTS_ + m0 + tq * 16;
            *(bf16x8*)dst = v0;
            *(bf16x8*)(dst + 8) = v1;
        }
        return;
    }
    // xm path: stage rows [m0-16, m0+64)
#pragma unroll
    for (int i = 0; i < 2; ++i)
#pragma unroll
        for (int j = 0; j < 2; ++j)
#pragma unroll
            for (int g = 0; g < 4; ++g) {
                const int srow = 16 + (wm - m0) + i * 16 + kq * 4 + g;
                const int scol = (wn - n0) + j * 16 + r;
                sxm[srow][scol] = f2bs(acc[i][j][g]);
            }
#pragma unroll
    for (int j = 0; j < 2; ++j)
#pragma unroll
        for (int g = 0; g < 4; ++g) {
            const int srow = kq * 4 + g;               // rows m0-16..m0-1
            const int scol = (wn - n0) + j * 16 + r;
            sxm[srow][scol] = f2bs(accx[j][g]);
        }
    __syncthreads();
    // conv + silu -> xcb (normal) + conv_s (for transpose)
    for (int e = threadIdx.x; e < 64 * 64; e += 256) {
        const int col = e & 63, rrel = e >> 6;
        const int grow = m0 + rrel;
        const int t = grow & (T_ - 1);
        const int d = n0 + col;
        const float4 w4 = ((const float4*)cw)[d];
        float a = cb[d];
#pragma unroll
        for (int k = 0; k < DC_; ++k) {
            if (t - 3 + k >= 0) {
                const float wk = (k == 0) ? w4.x : (k == 1) ? w4.y
                               : (k == 2) ? w4.z : w4.w;
                a += wk * bs2f(sxm[16 + rrel - 3 + k][col]);
            }
        }
        const unsigned short ov = f2bs(silu_f(a));
        xcb[(size_t)grow * DI_ + d] = ov;
        conv_s[rrel][col] = ov;
    }
    __syncthreads();
    // transposed write: xcbT[n0+dcol][m0 + tq*16 .. +15]
    {
        const int dcol = threadIdx.x >> 2, tq = threadIdx.x & 3;
        bf16x8 v0, v1;
#pragma unroll
        for (int j = 0; j < 8; ++j) {
            v0[j] = (short)conv_s[tq * 16 + j][dcol];
            v1[j] = (short)conv_s[tq * 16 + 8 + j][dcol];
        }
        unsigned short* dst = xcbT + (size_t)(n0 + dcol) * XTS_ + m0 + tq * 16;
        *(bf16x8*)dst = v0;
        *(bf16x8*)(dst + 8) = v1;
    }
}

// ---------------------------------------------------------------------------
// xp GEMM (unchanged, reads normal xcb).
// ---------------------------------------------------------------------------
__global__ __launch_bounds__(256) void xp_kernel(
    const unsigned short* __restrict__ xcb, const unsigned short* __restrict__ Wb,
    float* __restrict__ dbc)
{
    __shared__ float red[4][16][64];
    const int tid = threadIdx.x;
    const int wid = tid >> 6, lane = tid & 63;
    const int r = lane & 15, kq = lane >> 4;
    const int m0 = blockIdx.x * 16;
    f32x4 acc4[4] = {};
    const int k00 = wid * 256;
#pragma unroll
    for (int ks = 0; ks < 8; ++ks) {
        const int k0 = k00 + ks * 32;
        const bf16x8 a = *(const bf16x8*)(xcb + (size_t)(m0 + r) * DI_ + k0 + kq * 8);
#pragma unroll
        for (int j = 0; j < 4; ++j) {
            const bf16x8 bfr = *(const bf16x8*)(Wb + (size_t)(j * 16 + r) * DI_ + k0 + kq * 8);
            acc4[j] = __builtin_amdgcn_mfma_f32_16x16x32_bf16(a, bfr, acc4[j], 0, 0, 0);
        }
    }
#pragma unroll
    for (int j = 0; j < 4; ++j)
#pragma unroll
        for (int g = 0; g < 4; ++g)
            red[wid][kq * 4 + g][j * 16 + r] = acc4[j][g];
    __syncthreads();
    for (int i = tid; i < 1024; i += 256) {
        const int row = i >> 6, col = i & 63;
        const float s = red[0][row][col] + red[1][row][col] +
                        red[2][row][col] + red[3][row][col];
        dbc[(size_t)(m0 + row) * 64 + col] = s;
    }
}

// ---------------------------------------------------------------------------
// Fused selective scan (R13 geometry; u/z now ONE bf16x8 vector load per
// thread per chunk from the transposed buffers — off the recurrence path).
// ---------------------------------------------------------------------------
__global__ __launch_bounds__(256, 3) void scan_kernel(
    const unsigned short* __restrict__ xcbT, const float* __restrict__ dbc,
    const float* __restrict__ dtw, const float* __restrict__ dtbias,
    const float* __restrict__ A_log, const float* __restrict__ Dp,
    const unsigned short* __restrict__ zsT, unsigned short* __restrict__ ygb)
{
    __shared__ float dlt_s[T_][DL3_ + 1];
    __shared__ float Sl[CH3_][DL3_][17];
    __shared__ float Pl[CH3_][DL3_][17];
    const int tid = threadIdx.x;
    const int dl = tid & (DL3_ - 1);
    const int c = tid >> 3;
    const int b = blockIdx.x >> 7;
    const int d = (blockIdx.x & 127) * DL3_ + dl;
    const int row0 = b * T_ + c * TC3_;
    // u for this thread's whole chunk: one 16B load
    const bf16x8 uv = *(const bf16x8*)(xcbT + (size_t)d * XTS_ + b * T_ + c * TC3_);
    {
        const float4* Wp = (const float4*)(dtw + (size_t)d * R_);
        float4 w4[8];
#pragma unroll
        for (int q = 0; q < 8; ++q) w4[q] = Wp[q];
        const float bias = dtbias[d];
#pragma unroll
        for (int t = 0; t < TC3_; ++t) {
            const float4* Ap = (const float4*)(dbc + (size_t)(row0 + t) * 64);
            float acc = bias;
#pragma unroll
            for (int q = 0; q < 8; ++q) {
                const float4 a4 = Ap[q];
                acc += a4.x * w4[q].x + a4.y * w4[q].y + a4.z * w4[q].z + a4.w * w4[q].w;
            }
            dlt_s[c * TC3_ + t][dl] = softplus_f(acc);
        }
    }
    float Av[N_];
    {
        const float4* Alp = (const float4*)(A_log + (size_t)d * N_);
#pragma unroll
        for (int q = 0; q < 4; ++q) {
            const float4 v = Alp[q];
            Av[q * 4 + 0] = -__expf(v.x);
            Av[q * 4 + 1] = -__expf(v.y);
            Av[q * 4 + 2] = -__expf(v.z);
            Av[q * 4 + 3] = -__expf(v.w);
        }
    }
    __syncthreads();
    const float* bc = dbc + (size_t)row0 * 64;
    float h[N_];
#pragma unroll
    for (int n = 0; n < N_; ++n) h[n] = 0.f;
    float dsum = 0.f;
#pragma unroll
    for (int t = 0; t < TC3_; ++t) {
        const float dt_t = dlt_s[c * TC3_ + t][dl];
        dsum += dt_t;
        const float dbu = dt_t * bs2f((unsigned short)uv[t]);
#pragma unroll
        for (int q = 0; q < 4; ++q) {
            const float4 b4 = *(const float4*)(bc + t * 64 + R_ + q * 4);
            h[q * 4 + 0] = __expf(dt_t * Av[q * 4 + 0]) * h[q * 4 + 0] + dbu * b4.x;
            h[q * 4 + 1] = __expf(dt_t * Av[q * 4 + 1]) * h[q * 4 + 1] + dbu * b4.y;
            h[q * 4 + 2] = __expf(dt_t * Av[q * 4 + 2]) * h[q * 4 + 2] + dbu * b4.z;
            h[q * 4 + 3] = __expf(dt_t * Av[q * 4 + 3]) * h[q * 4 + 3] + dbu * b4.w;
        }
    }
#pragma unroll
    for (int n = 0; n < N_; ++n) {
        Sl[c][dl][n] = h[n];
        Pl[c][dl][n] = __expf(Av[n] * dsum);
    }
    __syncthreads();
    if (tid < DL3_ * N_) {
        const int dd = tid >> 4, nn = tid & 15;
        float hin = 0.f;
#pragma unroll
        for (int c2 = 0; c2 < CH3_; ++c2) {
            const float t2 = Pl[c2][dd][nn] * hin + Sl[c2][dd][nn];
            Sl[c2][dd][nn] = hin;
            hin = t2;
        }
    }
    __syncthreads();
#pragma unroll
    for (int n = 0; n < N_; ++n) h[n] = Sl[c][dl][n];
    const float Dd = Dp[d];
    const bf16x8 zv = *(const bf16x8*)(zsT + (size_t)d * XTS_ + b * T_ + c * TC3_);
    unsigned short* yp = ygb + (size_t)row0 * DI_ + d;
#pragma unroll
    for (int t = 0; t < TC3_; ++t) {
        const float dt_t = dlt_s[c * TC3_ + t][dl];
        const float ut = bs2f((unsigned short)uv[t]);
        const float dbu = dt_t * ut;
        float y = ut * Dd;
#pragma unroll
        for (int q = 0; q < 4; ++q) {
            const float4 b4 = *(const float4*)(bc + t * 64 + R_ + q * 4);
            const float4 c4 = *(const float4*)(bc + t * 64 + R_ + N_ + q * 4);
            h[q * 4 + 0] = __expf(dt_t * Av[q * 4 + 0]) * h[q * 4 + 0] + dbu * b4.x;
            h[q * 4 + 1] = __expf(dt_t * Av[q * 4 + 1]) * h[q * 4 + 1] + dbu * b4.y;
            h[q * 4 + 2] = __expf(dt_t * Av[q * 4 + 2]) * h[q * 4 + 2] + dbu * b4.z;
            h[q * 4 + 3] = __expf(dt_t * Av[q * 4 + 3]) * h[q * 4 + 3] + dbu * b4.w;
            y += h[q * 4 + 0] * c4.x + h[q * 4 + 1] * c4.y
               + h[q * 4 + 2] * c4.z + h[q * 4 + 3] * c4.w;
        }
        yp[t * DI_] = f2bs(y * bs2f((unsigned short)zv[t]));
    }
}

// ---------------------------------------------------------------------------
// out_proj split-K=2 (R13).
// ---------------------------------------------------------------------------
__global__ __launch_bounds__(256) void outproj_kernel(
    const unsigned short* __restrict__ A, const unsigned short* __restrict__ W,
    float* __restrict__ p)
{
    const int lane = threadIdx.x & 63, wid = threadIdx.x >> 6;
    const int r = lane & 15, kq = lane >> 4;
    const int wm = blockIdx.y * 64 + (wid >> 1) * 32;
    const int wn = blockIdx.x * 64 + (wid & 1) * 32;
    const int kb = blockIdx.z * 512;
    f32x4 acc[2][2] = {};
#pragma unroll 4
    for (int k0 = 0; k0 < 512; k0 += 32) {
        bf16x8 a[2], b[2];
#pragma unroll
        for (int i = 0; i < 2; ++i)
            a[i] = *(const bf16x8*)(A + (size_t)(wm + i * 16 + r) * DI_ + kb + k0 + kq * 8);
#pragma unroll
        for (int j = 0; j < 2; ++j)
            b[j] = *(const bf16x8*)(W + (size_t)(wn + j * 16 + r) * DI_ + kb + k0 + kq * 8);
#pragma unroll
        for (int i = 0; i < 2; ++i)
#pragma unroll
            for (int j = 0; j < 2; ++j)
                acc[i][j] = __builtin_amdgcn_mfma_f32_16x16x32_bf16(a[i], b[j], acc[i][j], 0, 0, 0);
    }
#pragma unroll
    for (int i = 0; i < 2; ++i)
#pragma unroll
        for (int j = 0; j < 2; ++j)
#pragma unroll
            for (int g = 0; g < 4; ++g) {
                const int row = wm + i * 16 + kq * 4 + g;
                const int col = wn + j * 16 + r;
                p[(size_t)blockIdx.z * (1024 * 512) + (size_t)row * 512 + col] = acc[i][j][g];
            }
}

// ---------------------------------------------------------------------------
// Heads
// ---------------------------------------------------------------------------
__global__ __launch_bounds__(256) void heads_kernel(
    const float* __restrict__ xn,
    const float* __restrict__ ps_w, const float* __restrict__ ps_b,
    const float* __restrict__ pa_w, const float* __restrict__ pa_b,
    float* __restrict__ out)
{
    const int idx = blockIdx.x * 4 + (threadIdx.x >> 6);
    const int lane = threadIdx.x & 63;
    const int bl = idx / 23, j = idx % 23;
    const float* tok;
    const float* wrow;
    float bias;
    float* dst;
    if (j < SD_) {
        tok = xn + ((size_t)bl * 4 + 3) * D_;
        wrow = ps_w + (size_t)j * D_;
        bias = ps_b[j];
        dst = out + (size_t)bl * SD_ + j;
    } else {
        const int jj = j - SD_;
        tok = xn + ((size_t)bl * 4 + 2) * D_;
        wrow = pa_w + (size_t)jj * D_;
        bias = pa_b[jj];
        dst = out + (size_t)B_ * L_ * SD_ + (size_t)bl * AD_ + jj;
    }
    float s = 0.f;
    for (int dd = lane; dd < D_; dd += 64) s += tok[dd] * wrow[dd];
#pragma unroll
    for (int off = 1; off < 64; off <<= 1) s += __shfl_xor(s, off);
    if (lane == 0) *dst = s + bias;
}

// ---------------------------------------------------------------------------
extern "C" void kernel_launch(void* const* d_in, const int* in_sizes, int n_in,
                              void* d_out, int out_size, void* d_ws, size_t ws_size,
                              hipStream_t stream)
{
    const float* states  = (const float*)d_in[0];
    const float* actions = (const float*)d_in[1];
    const float* rtg     = (const float*)d_in[2];
    const float* ctg     = (const float*)d_in[3];
    const int*   ts      = (const int*)d_in[4];
    const float* es_w = (const float*)d_in[5];  const float* es_b = (const float*)d_in[6];
    const float* ea_w = (const float*)d_in[7];  const float* ea_b = (const float*)d_in[8];
    const float* er_w = (const float*)d_in[9];  const float* er_b = (const float*)d_in[10];
    const float* ec_w = (const float*)d_in[11]; const float* ec_b = (const float*)d_in[12];
    const float* et_w = (const float*)d_in[13];
    const float* ln_w = (const float*)d_in[14]; const float* ln_b = (const float*)d_in[15];
    const float* in_w = (const float*)d_in[16];
    const float* conv_w = (const float*)d_in[17]; const float* conv_b = (const float*)d_in[18];
    const float* xp_w = (const float*)d_in[19];
    const float* dtp_w = (const float*)d_in[20]; const float* dtp_b = (const float*)d_in[21];
    const float* A_log = (const float*)d_in[22]; const float* Dp = (const float*)d_in[23];
    const float* out_w = (const float*)d_in[24];
    const float* fn_w = (const float*)d_in[25]; const float* fn_b = (const float*)d_in[26];
    const float* ps_w = (const float*)d_in[27]; const float* ps_b = (const float*)d_in[28];
    const float* pa_w = (const float*)d_in[29]; const float* pa_b = (const float*)d_in[30];
    float* out = (float*)d_out;

    // workspace layout
    float* ws   = (float*)d_ws;
    float* x    = ws;                    // 524288 f32
    float* xn   = x + 524288;            // 524288 f32 (final LN out)
    float* p    = xn + 524288;           // 1048576 f32 (out_proj partials p0|p1)
    float* dbc  = p + 1048576;           // 65536 f32
    unsigned short* xnb  = (unsigned short*)(dbc + 65536);  // 524288 bf16
    unsigned short* xcb  = xnb + 524288;                    // 1048576 bf16
    unsigned short* xcbT = xcb + 1048576;                   // DI*XTS = 1056768 bf16
    unsigned short* zsT  = xcbT + (size_t)DI_ * XTS_;       // 1056768 bf16
    unsigned short* ygb  = zsT + (size_t)DI_ * XTS_;        // 1048576 bf16
    unsigned short* wb   = ygb + 1048576;                   // 6553600 bf16
    unsigned short* wb_in  = wb;
    unsigned short* wb_out = wb + NW_IN;
    unsigned short* wb_xp  = wb + NW_IN + NW_OUT;

    init_kernel<<<WCVT_BLOCKS + B_ * L_, 256, 0, stream>>>(
        in_w, out_w, xp_w, wb,
        states, actions, rtg, ctg, ts,
        es_w, es_b, ea_w, ea_b, er_w, er_b, ec_w, ec_b, et_w, x);

    for (int i = 0; i < NL_; ++i) {
        if (i == 0)
            ln2_kernel<0><<<B_ * T_, 256, 0, stream>>>(
                x, nullptr, nullptr, ln_w, ln_b, xnb);
        else
            ln2_kernel<1><<<B_ * T_, 256, 0, stream>>>(
                x, p, p + 524288, ln_w + i * D_, ln_b + i * D_, xnb);
        // in_proj + conv + silu fused -> xcb, xcbT | zsT
        inproj_kernel<<<dim3(32, 16), 256, 0, stream>>>(
            xnb, wb_in + (size_t)i * 2 * DI_ * D_,
            conv_w + i * DI_ * DC_, conv_b + i * DI_, xcb, xcbT, zsT);
        // xp GEMM -> dbc
        xp_kernel<<<64, 256, 0, stream>>>(
            xcb, wb_xp + (size_t)i * 64 * DI_, dbc);
        // fused delta + chunked scan + gate -> ygb (vector u/z loads)
        scan_kernel<<<B_ * (DI_ / DL3_), 256, 0, stream>>>(
            xcbT, dbc, dtp_w + (size_t)i * DI_ * R_, dtp_b + i * DI_,
            A_log + (size_t)i * DI_ * N_, Dp + i * DI_, zsT, ygb);
        // out_proj split-K=2 -> p0|p1 (summed in next ln)
        outproj_kernel<<<dim3(8, 16, 2), 256, 0, stream>>>(
            ygb, wb_out + (size_t)i * D_ * DI_, p);
    }

    ln2_kernel<2><<<B_ * T_, 256, 0, stream>>>(x, p, p + 524288, fn_w, fn_b, xn);
    heads_kernel<<<(B_ * L_ * 23) / 4, 256, 0, stream>>>(xn, ps_w, ps_b, pa_w, pa_b, out);
}